// Round 12
// baseline (187.423 us; speedup 1.0000x reference)
//
#include <hip/hip_runtime.h>

// CCAMDec: out = x + scale * softmax(max_k(E)-E) @ y,  E = x·yᵀ over HW
// N=8, C=512, K=64, HW=4096. softmax(max-E) == softmax(-E) (shift invariance).
#define N_ 8
#define C_ 512
#define K_ 64
#define HW_ 4096
#define SCHUNK 128              // s per staged chunk
#define NCH 16                  // chunks per half (2048 s)

typedef __attribute__((ext_vector_type(8))) short short8;   // 8 bf16 (4 VGPRs) MFMA A/B frag
typedef __attribute__((ext_vector_type(4))) float floatx4;  // MFMA C/D frag

// 8 f32 -> 8 bf16 via hardware v_cvt_pk_bf16_f32 (RNE, 1 instr / 2 elems)
__device__ __forceinline__ short8 cvt8(const float* __restrict__ p){
  float4 u = *(const float4*)p;
  float4 w = *(const float4*)(p + 4);
  union { unsigned u32[4]; short8 s; } r;
  asm("v_cvt_pk_bf16_f32 %0, %1, %2" : "=v"(r.u32[0]) : "v"(u.x), "v"(u.y));
  asm("v_cvt_pk_bf16_f32 %0, %1, %2" : "=v"(r.u32[1]) : "v"(u.z), "v"(u.w));
  asm("v_cvt_pk_bf16_f32 %0, %1, %2" : "=v"(r.u32[2]) : "v"(w.x), "v"(w.y));
  asm("v_cvt_pk_bf16_f32 %0, %1, %2" : "=v"(r.u32[3]) : "v"(w.z), "v"(w.w));
  return r.s;
}

// async global -> LDS, 16 B/lane (1 KB/wave), zero VGPR cost
__device__ __forceinline__ void gload16(const void* g, void* l){
  __builtin_amdgcn_global_load_lds(
      (const __attribute__((address_space(1))) void*)g,
      (__attribute__((address_space(3))) void*)l, 16, 0, 0);
}

// K0: y (f32, [n][k][s]) -> ybf (bf16 row-major [n][k][s]) and ytr (bf16 [n][s][k])
__global__ __launch_bounds__(256) void k_prep(const float* __restrict__ y,
                                              unsigned short* __restrict__ ybf,
                                              unsigned short* __restrict__ ytr){
  __shared__ unsigned short tile[64][72];
  int n  = blockIdx.x >> 6;                 // 64 s-tiles per batch
  int s0 = (blockIdx.x & 63) << 6;
  int tid = threadIdx.x;
  int k  = tid >> 2;
  int sc = (tid & 3) << 4;
  const float* yp = y + ((size_t)n * K_ + k) * HW_ + s0 + sc;
  union { unsigned short u16[16]; short8 s8[2]; uint4 q[2]; } u;
  u.s8[0] = cvt8(yp);
  u.s8[1] = cvt8(yp + 8);
  unsigned short* rp = ybf + ((size_t)n * K_ + k) * HW_ + s0 + sc;
  *(uint4*)rp       = u.q[0];
  *(uint4*)(rp + 8) = u.q[1];
#pragma unroll
  for (int j = 0; j < 16; ++j) tile[sc + j][k] = u.u16[j];
  __syncthreads();
  int s  = tid >> 2;
  int kc = (tid & 3) << 4;
  unsigned short* tp = ytr + ((size_t)n * HW_ + s0 + s) * K_ + kc;
  *(uint4*)tp       = *(const uint4*)&tile[s][kc];
  *(uint4*)(tp + 8) = *(const uint4*)&tile[s][kc + 8];
}

// K1: fused energy + softmax + PV + residual at 2 blocks/CU.
// Grid 512 = (n, 16c-tile, s-half).  512 thr (8 waves).  48 KB LDS:
// 2-buffer staging [A 8K | B 16K] x2; Els/attl/T aliased in after phase E.
// Phase E: 16 chunks of 128 s, gload_lds + counted vmcnt(3), 2 s_barriers.
// Phase S: local h-reduce -> publish 4KB E-partial (agent-scope atomics) ->
//          flag spin for partner block (same n,ct, other half) -> softmax.
//          Deadlock-safe: LDS 48K + VGPR<=128 => >=2 blocks/CU => all 512
//          co-resident.  Flags zeroed per launch via hipMemsetAsync.
// Phase P: wave w owns 256 s of the half; 2-deep reg pipeline; T-transpose
//          -> 256B-contiguous x-load(L3)/out-store.
__global__ __launch_bounds__(512, 4) void k_fused(const float* __restrict__ x,
                                                  const unsigned short* __restrict__ ybf,
                                                  const unsigned short* __restrict__ ytr,
                                                  const float* __restrict__ scale,
                                                  unsigned* __restrict__ flags,
                                                  float* __restrict__ epart,
                                                  float* __restrict__ out){
  __shared__ char smem[49152];

  const int b = blockIdx.x;
  const int n = b >> 6, ct = (b >> 1) & 31, half = b & 1;
  const int tid = threadIdx.x;
  const int w = tid >> 6, l = tid & 63;
  const int lo = l & 15, hi = l >> 4;
  const int h = w >> 2, q = w & 3;
  const int c0 = ct << 4;
  const int sb = half << 11;       // half's s-base (2048)
  const int pairid = (n << 5) + ct;

  float sc = scale[0];
  asm volatile("" :: "v"(sc));     // force completion: keep vmcnt counts clean

  // ---- Phase E staging addresses (chunk-invariant, pre-swizzled source) ----
  const int ar = (w << 1) + (l >> 5);            // A: wave w covers c-rows 2w,2w+1
  const char* asrc = (const char*)(x + ((size_t)n * C_ + c0 + ar) * HW_ + sb)
                     + ((16 * (l & 31)) ^ ((ar & 7) << 4));
  const int kb0 = ((w << 1) + 0) * 4 + (l >> 4); // B: wave w covers k-rows 8w..8w+7
  const int kb1 = ((w << 1) + 1) * 4 + (l >> 4);
  const char* bsrc0 = (const char*)(ybf + ((size_t)n * K_ + kb0) * HW_ + sb)
                      + ((16 * (l & 15)) ^ ((kb0 & 7) << 4));
  const char* bsrc1 = (const char*)(ybf + ((size_t)n * K_ + kb1) * HW_ + sb)
                      + ((16 * (l & 15)) ^ ((kb1 & 7) << 4));

  floatx4 acc = {0.f, 0.f, 0.f, 0.f};
  const int aswz = (lo & 7) << 4;
  const int brow = (q << 4) + lo;

#define AS(BUF) (smem + (BUF) * 24576)
#define BS(BUF) (smem + (BUF) * 24576 + 8192)
#define STAGE(BUF, CH)                                                         \
  {                                                                            \
    gload16(asrc  + (size_t)(CH) * (SCHUNK * 4), AS(BUF) + (w << 10));         \
    gload16(bsrc0 + (size_t)(CH) * (SCHUNK * 2), BS(BUF) + ((w << 1) << 10));  \
    gload16(bsrc1 + (size_t)(CH) * (SCHUNK * 2), BS(BUF) + (((w << 1) | 1) << 10)); \
  }

  STAGE(0, 0)

#pragma unroll
  for (int ch = 0; ch < NCH; ++ch){
    const int cur = ch & 1;
    if (ch + 1 < NCH){
      STAGE(cur ^ 1, ch + 1)
      asm volatile("s_waitcnt vmcnt(3)" ::: "memory");   // chunk ch complete
    } else {
      asm volatile("s_waitcnt vmcnt(0)" ::: "memory");
    }
    __builtin_amdgcn_s_barrier();
    __builtin_amdgcn_sched_barrier(0);
#pragma unroll
    for (int ss = 0; ss < 2; ++ss){
      int ao = (h << 8) + (ss << 7) + (hi << 5);     // s = h*64+ss*32+hi*8 (f32 bytes)
      const char* ab = AS(cur) + (lo << 9);
      float4 a0f = *(const float4*)(ab + ((ao     ) ^ aswz));
      float4 a1f = *(const float4*)(ab + ((ao + 16) ^ aswz));
      union { unsigned u32[4]; short8 s; } af;
      asm("v_cvt_pk_bf16_f32 %0, %1, %2" : "=v"(af.u32[0]) : "v"(a0f.x), "v"(a0f.y));
      asm("v_cvt_pk_bf16_f32 %0, %1, %2" : "=v"(af.u32[1]) : "v"(a0f.z), "v"(a0f.w));
      asm("v_cvt_pk_bf16_f32 %0, %1, %2" : "=v"(af.u32[2]) : "v"(a1f.x), "v"(a1f.y));
      asm("v_cvt_pk_bf16_f32 %0, %1, %2" : "=v"(af.u32[3]) : "v"(a1f.z), "v"(a1f.w));
      int bo = (h << 7) + (ss << 6) + (hi << 4);     // same s in bf16 bytes
      short8 bfr = *(const short8*)(BS(cur) + brow * 256 + (bo ^ aswz));
      // swapped: A = y-frag (M=k), B = x-frag (N=c) -> D col=lo->c, row->k
      acc = __builtin_amdgcn_mfma_f32_16x16x32_bf16(bfr, af.s, acc, 0, 0, 0);
    }
    __builtin_amdgcn_sched_barrier(0);
    __builtin_amdgcn_s_barrier();
  }
#undef STAGE

  // ---- Phase S: E partial [h][c=lo][k=q*16+hi*4+r] into aliased LDS ----
  float (*Els)[16][64] = (float (*)[16][64])smem;
  *(floatx4*)&Els[h][lo][(q << 4) + (hi << 2)] = acc;
  __syncthreads();

  float e0 = 0.f, e1 = 0.f, e2 = 0.f, e3 = 0.f;
  if (tid < 256){
    float4 t0 = *(const float4*)&Els[0][tid >> 4][(tid & 15) * 4];
    float4 t1 = *(const float4*)&Els[1][tid >> 4][(tid & 15) * 4];
    e0 = t0.x + t1.x; e1 = t0.y + t1.y; e2 = t0.z + t1.z; e3 = t0.w + t1.w;
    float* ep = epart + (((size_t)pairid << 1) + half) * 1024 + (tid << 2);
    __hip_atomic_store(ep + 0, e0, __ATOMIC_RELAXED, __HIP_MEMORY_SCOPE_AGENT);
    __hip_atomic_store(ep + 1, e1, __ATOMIC_RELAXED, __HIP_MEMORY_SCOPE_AGENT);
    __hip_atomic_store(ep + 2, e2, __ATOMIC_RELAXED, __HIP_MEMORY_SCOPE_AGENT);
    __hip_atomic_store(ep + 3, e3, __ATOMIC_RELAXED, __HIP_MEMORY_SCOPE_AGENT);
  }
  __threadfence();                 // release our partial
  __syncthreads();
  if (tid == 0){
    atomicAdd(&flags[pairid], 1u);                       // device-scope
    while (atomicAdd(&flags[pairid], 0u) < 2u)
      __builtin_amdgcn_s_sleep(1);
  }
  __syncthreads();
  __threadfence();                 // acquire partner's partial

  char* attl = smem + 8192;        // att 16c x 64k bf16, XOR-swizzled (alias)
  if (tid < 256){
    const float* ep = epart + (((size_t)pairid << 1) + (half ^ 1)) * 1024 + (tid << 2);
    e0 += __hip_atomic_load(ep + 0, __ATOMIC_RELAXED, __HIP_MEMORY_SCOPE_AGENT);
    e1 += __hip_atomic_load(ep + 1, __ATOMIC_RELAXED, __HIP_MEMORY_SCOPE_AGENT);
    e2 += __hip_atomic_load(ep + 2, __ATOMIC_RELAXED, __HIP_MEMORY_SCOPE_AGENT);
    e3 += __hip_atomic_load(ep + 3, __ATOMIC_RELAXED, __HIP_MEMORY_SCOPE_AGENT);
    int c = tid >> 4, j = tid & 15;
    float m = fminf(fminf(e0, e1), fminf(e2, e3));
#pragma unroll
    for (int off = 8; off; off >>= 1) m = fminf(m, __shfl_xor(m, off, 16));
    float p0 = __expf(m - e0), p1 = __expf(m - e1);
    float p2 = __expf(m - e2), p3 = __expf(m - e3);
    float s = p0 + p1 + p2 + p3;
#pragma unroll
    for (int off = 8; off; off >>= 1) s += __shfl_xor(s, off, 16);
    float inv = 1.f / s;
    unsigned d0, d1;
    asm("v_cvt_pk_bf16_f32 %0, %1, %2" : "=v"(d0) : "v"(p0 * inv), "v"(p1 * inv));
    asm("v_cvt_pk_bf16_f32 %0, %1, %2" : "=v"(d1) : "v"(p2 * inv), "v"(p3 * inv));
    uint2 dd; dd.x = d0; dd.y = d1;
    *(uint2*)(attl + c * 128 + ((8 * j) ^ ((c & 7) << 4))) = dd;
  }
  __syncthreads();

  // ---- Phase P: PV + residual.  Wave w: s in [sb + w*256, +256) ----
  short8 batt0 = *(const short8*)(attl + lo * 128 + ((     hi * 16) ^ ((lo & 7) << 4)));
  short8 batt1 = *(const short8*)(attl + lo * 128 + ((64 + hi * 16) ^ ((lo & 7) << 4)));
  const unsigned short* ybn = ytr + (size_t)n * HW_ * K_;
  const int sP = sb + (w << 8);
  float (*Tw)[68] = (float (*)[68])(smem + 16384 + w * 4352);  // alias (16x68 f32)
  size_t xb[4];
#pragma unroll
  for (int rg = 0; rg < 4; ++rg)
    xb[rg] = ((size_t)n * C_ + c0 + (rg << 2) + hi) * HW_ + sP + (lo << 2);

  short8 aA[8]; float4 xA[4];
  short8 aB[8]; float4 xB[4];

#define PVLOAD(G, AV, XV)                                                      \
  {                                                                            \
    int sg = sP + (G) * 64;                                                    \
    _Pragma("unroll")                                                          \
    for (int t = 0; t < 4; ++t){                                               \
      const unsigned short* ap = ybn + (size_t)(sg + t * 16 + lo) * K_ + (hi << 3); \
      AV[2 * t]     = *(const short8*)(ap);                                    \
      AV[2 * t + 1] = *(const short8*)(ap + 32);                               \
    }                                                                          \
    _Pragma("unroll")                                                          \
    for (int rg = 0; rg < 4; ++rg)                                             \
      XV[rg] = *(const float4*)(x + xb[rg] + (G) * 64);                        \
  }

#define PVCOMP(G, AV, XV)                                                      \
  {                                                                            \
    _Pragma("unroll")                                                          \
    for (int t = 0; t < 4; ++t){                                               \
      floatx4 a2 = {0.f, 0.f, 0.f, 0.f};                                       \
      a2 = __builtin_amdgcn_mfma_f32_16x16x32_bf16(AV[2 * t],     batt0, a2, 0, 0, 0); \
      a2 = __builtin_amdgcn_mfma_f32_16x16x32_bf16(AV[2 * t + 1], batt1, a2, 0, 0, 0); \
      *(floatx4*)&Tw[lo][t * 16 + (hi << 2)] = a2;   /* D: col=lo->c, row->s */ \
    }                                                                          \
    _Pragma("unroll")                                                          \
    for (int rg = 0; rg < 4; ++rg){                                            \
      float4 v  = *(const float4*)&Tw[(rg << 2) + hi][lo << 2];                \
      float4 xv = XV[rg];                                                      \
      float4 o;                                                                \
      o.x = xv.x + sc * v.x; o.y = xv.y + sc * v.y;                            \
      o.z = xv.z + sc * v.z; o.w = xv.w + sc * v.w;                            \
      *(float4*)(out + xb[rg] + (G) * 64) = o;                                 \
    }                                                                          \
  }

  PVLOAD(0, aA, xA)
  PVLOAD(1, aB, xB)
  PVCOMP(0, aA, xA)
  PVLOAD(2, aA, xA)
  PVCOMP(1, aB, xB)
  PVLOAD(3, aB, xB)
  PVCOMP(2, aA, xA)
  PVCOMP(3, aB, xB)
#undef PVLOAD
#undef PVCOMP
#undef AS
#undef BS
}

extern "C" void kernel_launch(void* const* d_in, const int* in_sizes, int n_in,
                              void* d_out, int out_size, void* d_ws, size_t ws_size,
                              hipStream_t stream){
  const float* x     = (const float*)d_in[0];
  const float* y     = (const float*)d_in[1];
  const float* scale = (const float*)d_in[2];
  float* out = (float*)d_out;

  // ws layout (12 MiB):
  //   flags : 256 u32  = 1 KiB   @ 0      (zeroed every launch)
  //   epart : 512*1024 f32 = 2 MiB @ 4 KiB
  //   ybf   : N*K*HW bf16 = 4 MiB @ 4 MiB
  //   ytr   : N*HW*K bf16 = 4 MiB @ 8 MiB
  char* ws = (char*)d_ws;
  unsigned*       flags = (unsigned*)(ws);
  float*          epart = (float*)(ws + 4096);
  unsigned short* ybf   = (unsigned short*)(ws + (4u<<20));
  unsigned short* ytr   = (unsigned short*)(ws + (8u<<20));

  hipMemsetAsync(flags, 0, 1024, stream);   // async, capture-legal
  k_prep  <<<N_ * (HW_/64), 256, 0, stream>>>(y, ybf, ytr);
  k_fused <<<N_ * 32 * 2,   512, 0, stream>>>(x, ybf, ytr, scale, flags, epart, out);
}

// Round 13
// 50.643 us; speedup vs baseline: 3.7009x; 3.7009x over previous
//
#include <hip/hip_runtime.h>

// CCAMDec: out = x + scale * softmax(max_k(E)-E) @ y,  E = x·yᵀ over HW
// N=8, C=512, K=64, HW=4096. softmax(max-E) == softmax(-E) (shift invariance).
#define N_ 8
#define C_ 512
#define K_ 64
#define HW_ 4096
#define SCHUNK 256              // s per staged chunk
#define NCH 16                  // chunks (full s = 4096)

typedef __attribute__((ext_vector_type(8))) short short8;   // 8 bf16 (4 VGPRs) MFMA A/B frag
typedef __attribute__((ext_vector_type(4))) float floatx4;  // MFMA C/D frag

// 8 f32 -> 8 bf16 via hardware v_cvt_pk_bf16_f32 (RNE, 1 instr / 2 elems)
__device__ __forceinline__ short8 cvt8(const float* __restrict__ p){
  float4 u = *(const float4*)p;
  float4 w = *(const float4*)(p + 4);
  union { unsigned u32[4]; short8 s; } r;
  asm("v_cvt_pk_bf16_f32 %0, %1, %2" : "=v"(r.u32[0]) : "v"(u.x), "v"(u.y));
  asm("v_cvt_pk_bf16_f32 %0, %1, %2" : "=v"(r.u32[1]) : "v"(u.z), "v"(u.w));
  asm("v_cvt_pk_bf16_f32 %0, %1, %2" : "=v"(r.u32[2]) : "v"(w.x), "v"(w.y));
  asm("v_cvt_pk_bf16_f32 %0, %1, %2" : "=v"(r.u32[3]) : "v"(w.z), "v"(w.w));
  return r.s;
}

// async global -> LDS, 16 B/lane (1 KB/wave), zero VGPR cost
__device__ __forceinline__ void gload16(const void* g, void* l){
  __builtin_amdgcn_global_load_lds(
      (const __attribute__((address_space(1))) void*)g,
      (__attribute__((address_space(3))) void*)l, 16, 0, 0);
}

// K0: y (f32, [n][k][s]) -> ybf (bf16 row-major [n][k][s]) and ytr (bf16 [n][s][k])
__global__ __launch_bounds__(256) void k_prep(const float* __restrict__ y,
                                              unsigned short* __restrict__ ybf,
                                              unsigned short* __restrict__ ytr){
  __shared__ unsigned short tile[64][72];
  int n  = blockIdx.x >> 6;                 // 64 s-tiles per batch
  int s0 = (blockIdx.x & 63) << 6;
  int tid = threadIdx.x;
  int k  = tid >> 2;
  int sc = (tid & 3) << 4;
  const float* yp = y + ((size_t)n * K_ + k) * HW_ + s0 + sc;
  union { unsigned short u16[16]; short8 s8[2]; uint4 q[2]; } u;
  u.s8[0] = cvt8(yp);
  u.s8[1] = cvt8(yp + 8);
  unsigned short* rp = ybf + ((size_t)n * K_ + k) * HW_ + s0 + sc;
  *(uint4*)rp       = u.q[0];
  *(uint4*)(rp + 8) = u.q[1];
#pragma unroll
  for (int j = 0; j < 16; ++j) tile[sc + j][k] = u.u16[j];
  __syncthreads();
  int s  = tid >> 2;
  int kc = (tid & 3) << 4;
  unsigned short* tp = ytr + ((size_t)n * HW_ + s0 + s) * K_ + kc;
  *(uint4*)tp       = *(const uint4*)&tile[s][kc];
  *(uint4*)(tp + 8) = *(const uint4*)&tile[s][kc + 8];
}

// K1: FUSED energy + softmax + PV + residual.  Grid 256 (1 block/CU),
// 1024 thr (16 waves = 4 waves/SIMD: 2x R11's TLP).  Block = (n,16c), full s.
//  Phase E: 16 chunks of 256 s, 2-buffer staging, UNIFORM 3 gload_lds per
//           wave per chunk (1 A-row + 2 B-pair-rows), counted vmcnt(3).
//           Wave (h=w>>2, q=w&3): s-quarter h, k-quadrant q; swapped MFMA
//           (A=y M=k, B=x N=c).  Els[4][16][64] partials.
//  Phase S: reduce over h, softmax(-E), att -> XOR-swizzled LDS.
//  Phase P: wave w owns s in [w*256,(w+1)*256); 4 groups of 64 s; 2-deep
//           named register pipeline (rule #20); T[16][68] transpose ->
//           256B-contiguous x-load(L3-hot)/out-store.
// LDS 114 KB: staging 96K (2 x [A 16K | B 32K]) | Els 16K | attl 2K;
// phase-P T tiles alias the staging region (drained by then).
__global__ __launch_bounds__(1024) void k_fused(const float* __restrict__ x,
                                                const unsigned short* __restrict__ ybf,
                                                const unsigned short* __restrict__ ytr,
                                                const float* __restrict__ scale,
                                                float* __restrict__ out){
  __shared__ char smem[116736];

  const int bid = ((blockIdx.x & 7) << 5) | (blockIdx.x >> 3);  // XCD swizzle (256%8==0)
  const int ct = bid & 31, n = bid >> 5;
  const int tid = threadIdx.x;
  const int w = tid >> 6, l = tid & 63;
  const int lo = l & 15, hi = l >> 4;
  const int h = w >> 2, q = w & 3;
  const int c0 = ct << 4;

  float sc = scale[0];
  asm volatile("" :: "v"(sc));      // force completion: keep vmcnt counts clean

  // ---- Phase E staging addresses (chunk-invariant, pre-swizzled source) ----
  // A: wave w loads c-row w (1024 B = 256 f32) -> one gload16.
  const char* asrc = (const char*)(x + ((size_t)n * C_ + c0 + w) * HW_)
                     + ((16 * l) ^ ((w & 7) << 4));
  // B: wave w loads k-row pairs {2w,2w+1} and {32+2w,32+2w+1} (512 B rows).
  const int kb = (w << 1) + (l >> 5);            // &7 identical for both pairs
  const char* bsrc0 = (const char*)(ybf + ((size_t)n * K_ + kb) * HW_)
                      + ((16 * (l & 31)) ^ ((kb & 7) << 4));
  const char* bsrc1 = bsrc0 + (size_t)32 * HW_ * 2;

  floatx4 acc = {0.f, 0.f, 0.f, 0.f};
  const int aswz = (lo & 7) << 4;
  const int brow = (q << 4) + lo;                // brow&7 == lo&7

#define AS(BUF) (smem + (BUF) * 49152)
#define BS(BUF) (smem + (BUF) * 49152 + 16384)
#define STAGE(BUF, CH)                                                         \
  {                                                                            \
    gload16(asrc  + (size_t)(CH) * (SCHUNK * 4), AS(BUF) + (w << 10));         \
    gload16(bsrc0 + (size_t)(CH) * (SCHUNK * 2), BS(BUF) + (w << 10));         \
    gload16(bsrc1 + (size_t)(CH) * (SCHUNK * 2), BS(BUF) + 16384 + (w << 10)); \
  }

  STAGE(0, 0)

#pragma unroll
  for (int ch = 0; ch < NCH; ++ch){
    const int cur = ch & 1;
    if (ch + 1 < NCH){
      STAGE(cur ^ 1, ch + 1)
      asm volatile("s_waitcnt vmcnt(3)" ::: "memory");   // chunk ch complete
    } else {
      asm volatile("s_waitcnt vmcnt(0)" ::: "memory");
    }
    __builtin_amdgcn_s_barrier();
    __builtin_amdgcn_sched_barrier(0);
#pragma unroll
    for (int ss = 0; ss < 2; ++ss){
      // wave's s-slice: s_local = h*64 + ss*32 + hi*8 (+j)
      int ao = (h << 8) + (ss << 7) + (hi << 5);       // f32 bytes, < 1024
      const char* ab = AS(cur) + (lo << 10);           // A row pitch 1024 B
      float4 a0f = *(const float4*)(ab + ((ao     ) ^ aswz));
      float4 a1f = *(const float4*)(ab + ((ao + 16) ^ aswz));
      union { unsigned u32[4]; short8 s; } af;
      asm("v_cvt_pk_bf16_f32 %0, %1, %2" : "=v"(af.u32[0]) : "v"(a0f.x), "v"(a0f.y));
      asm("v_cvt_pk_bf16_f32 %0, %1, %2" : "=v"(af.u32[1]) : "v"(a0f.z), "v"(a0f.w));
      asm("v_cvt_pk_bf16_f32 %0, %1, %2" : "=v"(af.u32[2]) : "v"(a1f.x), "v"(a1f.y));
      asm("v_cvt_pk_bf16_f32 %0, %1, %2" : "=v"(af.u32[3]) : "v"(a1f.z), "v"(a1f.w));
      int bo = (h << 7) + (ss << 6) + (hi << 4);       // bf16 bytes, < 512
      short8 bfr = *(const short8*)(BS(cur) + brow * 512 + (bo ^ aswz));
      // swapped: A = y-frag (M=k), B = x-frag (N=c) -> D col=lo->c, row->k
      acc = __builtin_amdgcn_mfma_f32_16x16x32_bf16(bfr, af.s, acc, 0, 0, 0);
    }
    __builtin_amdgcn_sched_barrier(0);
    __builtin_amdgcn_s_barrier();
  }
#undef STAGE

  // ---- Phase S: E partial [h][c=lo][k=q*16+hi*4+r] -> softmax ----
  float (*Els)[16][64] = (float (*)[16][64])(smem + 98304);
  *(floatx4*)&Els[h][lo][(q << 4) + (hi << 2)] = acc;
  __syncthreads();

  char* attl = smem + 114688;       // att 16c x 64k bf16, XOR-swizzled
  if (tid < 256){
    int c = tid >> 4, j = tid & 15;
    float4 t0 = *(const float4*)&Els[0][c][4 * j];
    float4 t1 = *(const float4*)&Els[1][c][4 * j];
    float4 t2 = *(const float4*)&Els[2][c][4 * j];
    float4 t3 = *(const float4*)&Els[3][c][4 * j];
    float e0 = t0.x + t1.x + t2.x + t3.x;
    float e1 = t0.y + t1.y + t2.y + t3.y;
    float e2 = t0.z + t1.z + t2.z + t3.z;
    float e3 = t0.w + t1.w + t2.w + t3.w;
    float m = fminf(fminf(e0, e1), fminf(e2, e3));
#pragma unroll
    for (int off = 8; off; off >>= 1) m = fminf(m, __shfl_xor(m, off, 16));
    float p0 = __expf(m - e0), p1 = __expf(m - e1);
    float p2 = __expf(m - e2), p3 = __expf(m - e3);
    float s = p0 + p1 + p2 + p3;
#pragma unroll
    for (int off = 8; off; off >>= 1) s += __shfl_xor(s, off, 16);
    float inv = 1.f / s;
    unsigned d0, d1;
    asm("v_cvt_pk_bf16_f32 %0, %1, %2" : "=v"(d0) : "v"(p0 * inv), "v"(p1 * inv));
    asm("v_cvt_pk_bf16_f32 %0, %1, %2" : "=v"(d1) : "v"(p2 * inv), "v"(p3 * inv));
    uint2 dd; dd.x = d0; dd.y = d1;
    *(uint2*)(attl + c * 128 + ((8 * j) ^ ((c & 7) << 4))) = dd;
  }
  __syncthreads();

  // ---- Phase P: PV + residual.  Wave w: s in [w*256, (w+1)*256) ----
  short8 batt0 = *(const short8*)(attl + lo * 128 + ((     hi * 16) ^ ((lo & 7) << 4)));
  short8 batt1 = *(const short8*)(attl + lo * 128 + ((64 + hi * 16) ^ ((lo & 7) << 4)));
  const unsigned short* ybn = ytr + (size_t)n * HW_ * K_;
  const int sP = w << 8;
  float (*Tw)[68] = (float (*)[68])(smem + w * 4352);   // alias staging (drained)
  size_t xb[4];
#pragma unroll
  for (int rg = 0; rg < 4; ++rg)
    xb[rg] = ((size_t)n * C_ + c0 + (rg << 2) + hi) * HW_ + sP + (lo << 2);

  short8 aA[8]; float4 xA[4];
  short8 aB[8]; float4 xB[4];

#define PVLOAD(G, AV, XV)                                                      \
  {                                                                            \
    int sg = sP + (G) * 64;                                                    \
    _Pragma("unroll")                                                          \
    for (int t = 0; t < 4; ++t){                                               \
      const unsigned short* ap = ybn + (size_t)(sg + t * 16 + lo) * K_ + (hi << 3); \
      AV[2 * t]     = *(const short8*)(ap);                                    \
      AV[2 * t + 1] = *(const short8*)(ap + 32);                               \
    }                                                                          \
    _Pragma("unroll")                                                          \
    for (int rg = 0; rg < 4; ++rg)                                             \
      XV[rg] = *(const float4*)(x + xb[rg] + (G) * 64);                        \
  }

#define PVCOMP(G, AV, XV)                                                      \
  {                                                                            \
    _Pragma("unroll")                                                          \
    for (int t = 0; t < 4; ++t){                                               \
      floatx4 a2 = {0.f, 0.f, 0.f, 0.f};                                       \
      a2 = __builtin_amdgcn_mfma_f32_16x16x32_bf16(AV[2 * t],     batt0, a2, 0, 0, 0); \
      a2 = __builtin_amdgcn_mfma_f32_16x16x32_bf16(AV[2 * t + 1], batt1, a2, 0, 0, 0); \
      *(floatx4*)&Tw[lo][t * 16 + (hi << 2)] = a2;   /* D: col=lo->c, row->s */ \
    }                                                                          \
    _Pragma("unroll")                                                          \
    for (int rg = 0; rg < 4; ++rg){                                            \
      float4 v  = *(const float4*)&Tw[(rg << 2) + hi][lo << 2];                \
      float4 xv = XV[rg];                                                      \
      float4 o;                                                                \
      o.x = xv.x + sc * v.x; o.y = xv.y + sc * v.y;                            \
      o.z = xv.z + sc * v.z; o.w = xv.w + sc * v.w;                            \
      *(float4*)(out + xb[rg] + (G) * 64) = o;                                 \
    }                                                                          \
  }

  PVLOAD(0, aA, xA)
  PVLOAD(1, aB, xB)
  PVCOMP(0, aA, xA)
  PVLOAD(2, aA, xA)
  PVCOMP(1, aB, xB)
  PVLOAD(3, aB, xB)
  PVCOMP(2, aA, xA)
  PVCOMP(3, aB, xB)
#undef PVLOAD
#undef PVCOMP
#undef AS
#undef BS
}

extern "C" void kernel_launch(void* const* d_in, const int* in_sizes, int n_in,
                              void* d_out, int out_size, void* d_ws, size_t ws_size,
                              hipStream_t stream){
  const float* x     = (const float*)d_in[0];
  const float* y     = (const float*)d_in[1];
  const float* scale = (const float*)d_in[2];
  float* out = (float*)d_out;

  // ws layout (8 MiB total):
  //   ybf : N*K*HW bf16 = 4 MiB  @ 0
  //   ytr : N*HW*K bf16 = 4 MiB  @ 4 MiB
  char* ws = (char*)d_ws;
  unsigned short* ybf = (unsigned short*)(ws);
  unsigned short* ytr = (unsigned short*)(ws + (4u<<20));

  k_prep  <<<N_ * (HW_/64), 256,  0, stream>>>(y, ybf, ytr);
  k_fused <<<N_ * 32,       1024, 0, stream>>>(x, ybf, ytr, scale, out);
}